// Round 6
// baseline (240.273 us; speedup 1.0000x reference)
//
#include <hip/hip_runtime.h>
#include <hip/hip_bf16.h>
#include <math.h>

#define B_ 64
#define P_ 128
#define C_ 72
#define PADC 80    // f16 global row stride for A/Bc
#define BCS 88     // LDS row stride in halfs (176B -> 2-way banks, free)
#define IT 8       // i-rows per edge block

typedef __attribute__((ext_vector_type(8))) _Float16 half8v;
typedef __attribute__((ext_vector_type(4))) float f32x4;
typedef __attribute__((ext_vector_type(2))) float f32x2;
typedef __attribute__((ext_vector_type(4))) unsigned int u32x4;

// precomputed weight-fragment table (units: half8v, 64 per fragment)
#define FRAG_WE2  0          // We2 (+be2 @k=72), 15 frags
#define FRAG_WE1A (15 * 64)  // We1 rows 0..71, 15 frags
#define FRAG_WE1B (30 * 64)  // We1 rows 72..143 (+be1 @k=72), 15 frags
#define FRAG_WH1  (45 * 64)  // Wh1 (+bh1 @k=144), 25 frags
#define FRAG_WH2  (70 * 64)  // Wh2 (+bh2 @k=72), 15 frags
#define NFRAG 85

__device__ __forceinline__ float psi_f(float v) {
    float a = fabsf(v);
    return copysignf(__logf(1.0f + a), v);
}
template <int CTRL>
__device__ __forceinline__ float dpp_add(float v) {
    int s = __builtin_amdgcn_update_dpp(0, __builtin_bit_cast(int, v), CTRL, 0xF, 0xF, true);
    return v + __builtin_bit_cast(float, s);
}
// full sum across each 16-lane group (fixed tree -> deterministic)
__device__ __forceinline__ float red16(float v) {
    v = dpp_add<0xB1>(v);    // quad_perm(1,0,3,2)
    v = dpp_add<0x4E>(v);    // quad_perm(2,3,0,1)
    v = dpp_add<0x141>(v);   // row_half_mirror
    v = dpp_add<0x140>(v);   // row_mirror
    return v;
}
__device__ __forceinline__ half8v cvt8(const float* p) {
    f32x4 a = *(const f32x4*)p;
    f32x4 b = *(const f32x4*)(p + 4);
    half8v r = {(_Float16)a[0], (_Float16)a[1], (_Float16)a[2], (_Float16)a[3],
                (_Float16)b[0], (_Float16)b[1], (_Float16)b[2], (_Float16)b[3]};
    return r;
}

// ---------------- Kernel 0: build all weight fragments ------------------
__global__ __launch_bounds__(64) void setup_kernel(
    const float* __restrict__ We1, const float* __restrict__ be1,
    const float* __restrict__ We2, const float* __restrict__ be2,
    const float* __restrict__ Wh1, const float* __restrict__ bh1,
    const float* __restrict__ Wh2, const float* __restrict__ bh2,
    half8v* __restrict__ frags)
{
    const int bid = blockIdx.x;
    const int l = threadIdx.x;
    const int c16 = l & 15, g = l >> 4;

    const float* W;
    const float* bias;
    int kmax, rel;
    if (bid < 15)      { W = We2;            bias = be2;     kmax = 72;  rel = bid; }
    else if (bid < 30) { W = We1;            bias = nullptr; kmax = 72;  rel = bid - 15; }
    else if (bid < 45) { W = We1 + 72 * C_;  bias = be1;     kmax = 72;  rel = bid - 30; }
    else if (bid < 70) { W = Wh1;            bias = bh1;     kmax = 144; rel = bid - 45; }
    else               { W = Wh2;            bias = bh2;     kmax = 72;  rel = bid - 70; }
    const int kt = rel / 5, nt = rel - 5 * kt;
    const int n = nt * 16 + c16;

    half8v f = {};
    if (n < C_) {
        #pragma unroll
        for (int jj = 0; jj < 8; ++jj) {
            int k = kt * 32 + g * 8 + jj;
            float w = 0.f;
            if (k < kmax) w = W[k * C_ + n];
            else if (k == kmax && bias) w = bias[n];
            f[jj] = (_Float16)w;
        }
    }
    frags[bid * 64 + l] = f;
}

// ---------------- Kernel 1: pre (MFMA, precomputed frags) ---------------
// [16 h-rows] @ We1 halves -> A and Bc(+be1), f16 padded-80.
__global__ __launch_bounds__(64) void pre_kernel(
    const float* __restrict__ h, const half8v* __restrict__ frags,
    _Float16* __restrict__ Ah, _Float16* __restrict__ Bch)
{
    const int l = threadIdx.x, c16 = l & 15, g = l >> 4;
    const int m0 = blockIdx.x * 16;

    const float* hrow = h + (m0 + c16) * C_;
    half8v a0 = cvt8(hrow + g * 8);
    half8v a1 = cvt8(hrow + 32 + g * 8);
    half8v a2 = {};
    if (g == 0) a2 = cvt8(hrow + 64);
    else if (g == 1) a2[0] = (_Float16)1.0f;   // bias row k=72

    #pragma unroll 1
    for (int sel = 0; sel < 2; ++sel) {
        const half8v* F = frags + (sel ? FRAG_WE1B : FRAG_WE1A);
        f32x4 acc[5] = {};
        #pragma unroll
        for (int kt = 0; kt < 3; ++kt) {
            half8v a = (kt == 0) ? a0 : (kt == 1 ? a1 : a2);
            #pragma unroll
            for (int nt = 0; nt < 5; ++nt)
                acc[nt] = __builtin_amdgcn_mfma_f32_16x16x32_f16(a, F[(kt * 5 + nt) * 64 + l], acc[nt], 0, 0, 0);
        }
        _Float16* dst = sel ? Bch : Ah;
        #pragma unroll
        for (int nt = 0; nt < 5; ++nt) {
            int n = nt * 16 + c16;
            if (n < C_) {
                #pragma unroll
                for (int r = 0; r < 4; ++r)
                    dst[(m0 + 4 * g + r) * PADC + n] = (_Float16)acc[nt][r];
            }
        }
    }
}

// ---------------- Kernel 2: edge MLP, lane = edge orientation -----------
__global__ __launch_bounds__(256, 4) void edge_kernel(
    const float* __restrict__ x, const _Float16* __restrict__ Ah,
    const _Float16* __restrict__ Bch, const float* __restrict__ We1,
    const half8v* __restrict__ frags,
    const float* __restrict__ Wm, const float* __restrict__ bm,
    const float* __restrict__ Wx,
    float* __restrict__ wm_out, float* __restrict__ xacc_out)
{
    __shared__ __align__(16) _Float16 A_s[IT][PADC];
    __shared__ __align__(16) _Float16 Bc_s[P_][BCS];
    __shared__ __align__(16) float xj_s[P_][4];
    __shared__ __align__(16) _Float16 w1_s[PADC], w2_s[PADC];

    const int b  = blockIdx.x >> 4;
    const int it = blockIdx.x & 15;
    const int t  = threadIdx.x;
    const int wv = t >> 6;
    const int l  = t & 63;
    const int c16 = l & 15;
    const int g   = l >> 4;

    // ---- stage to LDS ----
    {
        const unsigned int* Asrc = (const unsigned int*)(Ah + (b * P_ + it * IT) * PADC);
        for (int idx = t; idx < IT * PADC / 2; idx += 256)
            ((unsigned int*)A_s)[idx] = Asrc[idx];
        for (int cidx = t; cidx < P_ * 10; cidx += 256) {
            int r = cidx / 10, c = cidx - r * 10;
            *(u32x4*)&Bc_s[r][c * 8] = ((const u32x4*)(Bch + (b * P_ + r) * PADC))[c];
        }
        for (int idx = t; idx < P_ * 4; idx += 256)
            ((float*)xj_s)[idx] = x[b * P_ * 4 + idx];
        if (t < 160) {
            int hs = t >= 80;
            int c = t - hs * 80;
            float wv_ = (c < C_) ? We1[(144 + hs) * C_ + c] : 0.f;
            (hs ? w2_s : w1_s)[c] = (_Float16)wv_;
        }
    }
    __syncthreads();

    // ---- We2(+be2) fragments (A-operand), coalesced precomputed loads ----
    half8v Wf[3][5];
    #pragma unroll
    for (int kt = 0; kt < 3; ++kt)
        #pragma unroll
        for (int nt = 0; nt < 5; ++nt)
            Wf[kt][nt] = frags[FRAG_WE2 + (kt * 5 + nt) * 64 + l];

    // per-lane channel table: ch = nt*16 + 4g + r
    f32x2 WmWx[5][4];
    #pragma unroll
    for (int nt = 0; nt < 5; ++nt)
        #pragma unroll
        for (int r = 0; r < 4; ++r) {
            int ch = nt * 16 + 4 * g + r;
            bool ok = ch < C_;
            WmWx[nt][r][0] = ok ? Wm[ch] : 0.f;
            WmWx[nt][r][1] = ok ? Wx[ch] : 0.f;
        }
    const float bm0 = bm[0];

    #pragma unroll 1
    for (int ii = 0; ii < 2; ++ii) {
        const int iloc = wv * 2 + ii;
        const int i = it * IT + iloc;
        const int node_i = b * P_ + i;
        const f32x4 xi = *(const f32x4*)&xj_s[i][0];

        float wmacc[5][4] = {};
        f32x4 xacc = {0.f, 0.f, 0.f, 0.f};

        #pragma unroll 1
        for (int jt = 0; jt < 8; ++jt) {
            // ---- phase A: this lane's m1^T B-fragment chunks ----
            const int j = jt * 16 + c16;
            const f32x4 xjv = *(const f32x4*)&xj_s[j][0];
            float d0 = xi[0] - xjv[0], d1 = xi[1] - xjv[1];
            float d2 = xi[2] - xjv[2], d3 = xi[3] - xjv[3];
            float nn = d0 * d0 - d1 * d1 - d2 * d2 - d3 * d3;
            float pp = xi[0] * xjv[0] - xi[1] * xjv[1] - xi[2] * xjv[2] - xi[3] * xjv[3];
            _Float16 nh = (_Float16)psi_f(nn);
            _Float16 ph = (_Float16)psi_f(pp);
            half8v n8 = {nh, nh, nh, nh, nh, nh, nh, nh};
            half8v p8 = {ph, ph, ph, ph, ph, ph, ph, ph};
            half8v zero8 = {};

            auto chunk = [&](int k) -> half8v {
                half8v av = *(const half8v*)&A_s[iloc][k];
                half8v bv = *(const half8v*)&Bc_s[j][k];
                half8v w1 = *(const half8v*)&w1_s[k];
                half8v w2 = *(const half8v*)&w2_s[k];
                half8v v = av + bv;
                v = __builtin_elementwise_fma(w1, n8, v);
                v = __builtin_elementwise_fma(w2, p8, v);
                return __builtin_elementwise_max(v, zero8);
            };
            half8v af0 = chunk(g * 8);
            half8v af1 = chunk(32 + g * 8);
            half8v af2 = {};
            if (g == 0) af2 = chunk(64);
            else if (g == 1) af2[0] = (_Float16)1.0f;   // be2 bias row k=72

            // ---- phase B: D[ch][edge] = We2^T @ m1^T, 15 MFMAs ----
            f32x4 acc[5] = {};
            #pragma unroll
            for (int nt = 0; nt < 5; ++nt)
                acc[nt] = __builtin_amdgcn_mfma_f32_16x16x32_f16(Wf[0][nt], af0, acc[nt], 0, 0, 0);
            #pragma unroll
            for (int nt = 0; nt < 5; ++nt)
                acc[nt] = __builtin_amdgcn_mfma_f32_16x16x32_f16(Wf[1][nt], af1, acc[nt], 0, 0, 0);
            #pragma unroll
            for (int nt = 0; nt < 5; ++nt)
                acc[nt] = __builtin_amdgcn_mfma_f32_16x16x32_f16(Wf[2][nt], af2, acc[nt], 0, 0, 0);

            // ---- phase C: lane owns edge j; channels in registers ----
            f32x2 wdpd = {0.f, 0.f};
            #pragma unroll
            for (int nt = 0; nt < 5; ++nt)
                #pragma unroll
                for (int r = 0; r < 4; ++r) {
                    float v = fmaxf(acc[nt][r], 0.f);
                    acc[nt][r] = v;
                    f32x2 vv = {v, v};
                    wdpd = __builtin_elementwise_fma(vv, WmWx[nt][r], wdpd);
                }
            // reduce across the 4 g-groups (lanes xor 16, 32)
            {
                f32x2 s;
                s[0] = __shfl_xor(wdpd[0], 16, 64);
                s[1] = __shfl_xor(wdpd[1], 16, 64);
                wdpd += s;
                s[0] = __shfl_xor(wdpd[0], 32, 64);
                s[1] = __shfl_xor(wdpd[1], 32, 64);
                wdpd += s;
            }
            float w_ = __builtin_amdgcn_rcpf(1.f + __expf(-(wdpd[0] + bm0)));
            #pragma unroll
            for (int nt = 0; nt < 5; ++nt)
                #pragma unroll
                for (int r = 0; r < 4; ++r)
                    wmacc[nt][r] = fmaf(w_, acc[nt][r], wmacc[nt][r]);
            f32x4 pd4 = {wdpd[1], wdpd[1], wdpd[1], wdpd[1]};
            xacc = __builtin_elementwise_fma(pd4, xjv, xacc);
        } // jt

        // ---- finalize i: sum across the 16 edge-lanes of each row ----
        #pragma unroll
        for (int nt = 0; nt < 5; ++nt)
            #pragma unroll
            for (int r = 0; r < 4; ++r)
                wmacc[nt][r] = red16(wmacc[nt][r]);
        #pragma unroll
        for (int q = 0; q < 4; ++q) xacc[q] = red16(xacc[q]);

        if (c16 == 0) {
            #pragma unroll
            for (int nt = 0; nt < 5; ++nt)
                #pragma unroll
                for (int r = 0; r < 4; ++r) {
                    int ch = nt * 16 + 4 * g + r;
                    if (ch < C_) wm_out[node_i * C_ + ch] = wmacc[nt][r];
                }
        }
        if (l == 0)
            *(f32x4*)&xacc_out[node_i * 4] = xacc;
    } // ii
}

// ---------------- Kernel 3: node MLP (chained MFMAs, frag loads) --------
__global__ __launch_bounds__(64) void node_kernel(
    const float* __restrict__ x, const float* __restrict__ h,
    const half8v* __restrict__ frags,
    const float* __restrict__ wm, const float* __restrict__ xacc,
    float* __restrict__ hout, float* __restrict__ xout)
{
    __shared__ _Float16 g_s[16][BCS];
    const int l = threadIdx.x, c16 = l & 15, g = l >> 4;
    const int m0 = blockIdx.x * 16;

    const float* hrow  = h  + (m0 + c16) * C_;
    const float* wmrow = wm + (m0 + c16) * C_;

    // ---- GEMM1: [h|wm|1] (K=160) @ Wh1(+bh1 row 144) ----
    half8v a[5];
    #pragma unroll
    for (int kt = 0; kt < 5; ++kt) {
        int k = kt * 32 + g * 8;
        half8v v = {};
        if (k < C_) v = cvt8(hrow + k);
        else if (k < 144) v = cvt8(wmrow + (k - C_));
        else if (k == 144) v[0] = (_Float16)1.0f;
        a[kt] = v;
    }
    f32x4 acc1[5] = {};
    #pragma unroll
    for (int kt = 0; kt < 5; ++kt)
        #pragma unroll
        for (int nt = 0; nt < 5; ++nt)
            acc1[nt] = __builtin_amdgcn_mfma_f32_16x16x32_f16(
                a[kt], frags[FRAG_WH1 + (kt * 5 + nt) * 64 + l], acc1[nt], 0, 0, 0);

    // relu -> wave-local LDS transpose (D layout -> A-fragment layout)
    #pragma unroll
    for (int nt = 0; nt < 5; ++nt) {
        int n = nt * 16 + c16;
        #pragma unroll
        for (int r = 0; r < 4; ++r)
            g_s[4 * g + r][n] = (_Float16)fmaxf(acc1[nt][r], 0.f);
    }
    half8v b0 = *(const half8v*)&g_s[c16][g * 8];
    half8v b1 = *(const half8v*)&g_s[c16][32 + g * 8];
    half8v b2 = {};
    if (g == 0) b2 = *(const half8v*)&g_s[c16][64];
    else if (g == 1) b2[0] = (_Float16)1.0f;   // bh2 bias row k=72

    // ---- GEMM2: g (K=96) @ Wh2(+bh2 row 72) ----
    f32x4 acc2[5] = {};
    #pragma unroll
    for (int kt = 0; kt < 3; ++kt) {
        half8v aa = (kt == 0) ? b0 : (kt == 1 ? b1 : b2);
        #pragma unroll
        for (int nt = 0; nt < 5; ++nt)
            acc2[nt] = __builtin_amdgcn_mfma_f32_16x16x32_f16(
                aa, frags[FRAG_WH2 + (kt * 5 + nt) * 64 + l], acc2[nt], 0, 0, 0);
    }
    #pragma unroll
    for (int nt = 0; nt < 5; ++nt) {
        int n = nt * 16 + c16;
        if (n < C_) {
            #pragma unroll
            for (int r = 0; r < 4; ++r) {
                int row = m0 + 4 * g + r;
                hout[row * C_ + n] = h[row * C_ + n] + acc2[nt][r];
            }
        }
    }
    {
        int row = m0 + (l >> 2), d = l & 3;
        xout[row * 4 + d] = x[row * 4 + d] + 0.005f * (xacc[row * 4 + d] * (1.0f / 128.f));
    }
}

extern "C" void kernel_launch(void* const* d_in, const int* in_sizes, int n_in,
                              void* d_out, int out_size, void* d_ws, size_t ws_size,
                              hipStream_t stream) {
    const float* x   = (const float*)d_in[0];
    const float* h   = (const float*)d_in[1];
    const float* We1 = (const float*)d_in[2];
    const float* be1 = (const float*)d_in[3];
    const float* We2 = (const float*)d_in[4];
    const float* be2 = (const float*)d_in[5];
    const float* Wm  = (const float*)d_in[6];
    const float* bm  = (const float*)d_in[7];
    const float* Wh1 = (const float*)d_in[8];
    const float* bh1 = (const float*)d_in[9];
    const float* Wh2 = (const float*)d_in[10];
    const float* bh2 = (const float*)d_in[11];
    const float* Wx  = (const float*)d_in[12];

    const int NNODE = B_ * P_;                       // 8192
    _Float16* Ah  = (_Float16*)d_ws;                 // [8192][80] f16
    _Float16* Bch = Ah + NNODE * PADC;               // [8192][80] f16
    float* wm   = (float*)(Bch + NNODE * PADC);      // [8192][72] f32
    float* xacc = wm + NNODE * C_;                   // [8192][4]  f32
    half8v* frags = (half8v*)(xacc + NNODE * 4);     // 85 frags x 1KB

    float* hout = (float*)d_out;                     // [8192][72]
    float* xout = hout + NNODE * C_;                 // [8192][4]

    setup_kernel<<<NFRAG, 64, 0, stream>>>(We1, be1, We2, be2, Wh1, bh1, Wh2, bh2, frags);
    pre_kernel<<<NNODE / 16, 64, 0, stream>>>(h, frags, Ah, Bch);
    edge_kernel<<<B_ * 16, 256, 0, stream>>>(x, Ah, Bch, We1, frags,
                                             Wm, bm, Wx, wm, xacc);
    node_kernel<<<NNODE / 16, 64, 0, stream>>>(x, h, frags, wm, xacc, hout, xout);
}

// Round 7
// 61.815 us; speedup vs baseline: 3.8870x; 3.8870x over previous
//
#include <hip/hip_runtime.h>
#include <hip/hip_bf16.h>
#include <math.h>

#define B_ 64
#define P_ 128
#define C_ 72
#define PADC 80    // f16 global row stride for A/Bc
#define BCS 88     // LDS row stride in halfs (176B -> 2-way banks, free)
#define IT 8       // i-rows per edge block

typedef __attribute__((ext_vector_type(8))) _Float16 half8v;
typedef __attribute__((ext_vector_type(4))) float f32x4;
typedef __attribute__((ext_vector_type(2))) float f32x2;
typedef __attribute__((ext_vector_type(4))) unsigned int u32x4;

// precomputed weight-fragment table (units: half8v, 64 per fragment)
#define FRAG_WE2  0          // We2 (+be2 @k=72), 15 frags
#define FRAG_WE1A (15 * 64)  // We1 rows 0..71, 15 frags
#define FRAG_WE1B (30 * 64)  // We1 rows 72..143 (+be1 @k=72), 15 frags
#define FRAG_WH1  (45 * 64)  // Wh1 (+bh1 @k=144), 25 frags
#define FRAG_WH2  (70 * 64)  // Wh2 (+bh2 @k=72), 15 frags
#define NFRAG 85

__device__ __forceinline__ float psi_f(float v) {
    float a = fabsf(v);
    return copysignf(__logf(1.0f + a), v);
}
template <int CTRL>
__device__ __forceinline__ float dpp_add(float v) {
    int s = __builtin_amdgcn_update_dpp(0, __builtin_bit_cast(int, v), CTRL, 0xF, 0xF, true);
    return v + __builtin_bit_cast(float, s);
}
// full sum across each 16-lane group (fixed tree -> deterministic)
__device__ __forceinline__ float red16(float v) {
    v = dpp_add<0xB1>(v);    // quad_perm(1,0,3,2)
    v = dpp_add<0x4E>(v);    // quad_perm(2,3,0,1)
    v = dpp_add<0x141>(v);   // row_half_mirror
    v = dpp_add<0x140>(v);   // row_mirror
    return v;
}
__device__ __forceinline__ half8v cvt8(const float* p) {
    f32x4 a = *(const f32x4*)p;
    f32x4 b = *(const f32x4*)(p + 4);
    half8v r = {(_Float16)a[0], (_Float16)a[1], (_Float16)a[2], (_Float16)a[3],
                (_Float16)b[0], (_Float16)b[1], (_Float16)b[2], (_Float16)b[3]};
    return r;
}

// ---------------- Kernel 0: build all weight fragments ------------------
__global__ __launch_bounds__(64) void setup_kernel(
    const float* __restrict__ We1, const float* __restrict__ be1,
    const float* __restrict__ We2, const float* __restrict__ be2,
    const float* __restrict__ Wh1, const float* __restrict__ bh1,
    const float* __restrict__ Wh2, const float* __restrict__ bh2,
    half8v* __restrict__ frags)
{
    const int bid = blockIdx.x;
    const int l = threadIdx.x;
    const int c16 = l & 15, g = l >> 4;

    const float* W;
    const float* bias;
    int kmax, rel;
    if (bid < 15)      { W = We2;            bias = be2;     kmax = 72;  rel = bid; }
    else if (bid < 30) { W = We1;            bias = nullptr; kmax = 72;  rel = bid - 15; }
    else if (bid < 45) { W = We1 + 72 * C_;  bias = be1;     kmax = 72;  rel = bid - 30; }
    else if (bid < 70) { W = Wh1;            bias = bh1;     kmax = 144; rel = bid - 45; }
    else               { W = Wh2;            bias = bh2;     kmax = 72;  rel = bid - 70; }
    const int kt = rel / 5, nt = rel - 5 * kt;
    const int n = nt * 16 + c16;

    half8v f = {};
    if (n < C_) {
        #pragma unroll
        for (int jj = 0; jj < 8; ++jj) {
            int k = kt * 32 + g * 8 + jj;
            float w = 0.f;
            if (k < kmax) w = W[k * C_ + n];
            else if (k == kmax && bias) w = bias[n];
            f[jj] = (_Float16)w;
        }
    }
    frags[bid * 64 + l] = f;
}

// ---------------- Kernel 1: pre (MFMA, precomputed frags) ---------------
__global__ __launch_bounds__(64) void pre_kernel(
    const float* __restrict__ h, const half8v* __restrict__ frags,
    _Float16* __restrict__ Ah, _Float16* __restrict__ Bch)
{
    const int l = threadIdx.x, c16 = l & 15, g = l >> 4;
    const int m0 = blockIdx.x * 16;

    const float* hrow = h + (m0 + c16) * C_;
    half8v a0 = cvt8(hrow + g * 8);
    half8v a1 = cvt8(hrow + 32 + g * 8);
    half8v a2 = {};
    if (g == 0) a2 = cvt8(hrow + 64);
    else if (g == 1) a2[0] = (_Float16)1.0f;   // bias row k=72

    #pragma unroll 1
    for (int sel = 0; sel < 2; ++sel) {
        const half8v* F = frags + (sel ? FRAG_WE1B : FRAG_WE1A);
        f32x4 acc[5] = {};
        #pragma unroll
        for (int kt = 0; kt < 3; ++kt) {
            half8v a = (kt == 0) ? a0 : (kt == 1 ? a1 : a2);
            #pragma unroll
            for (int nt = 0; nt < 5; ++nt)
                acc[nt] = __builtin_amdgcn_mfma_f32_16x16x32_f16(a, F[(kt * 5 + nt) * 64 + l], acc[nt], 0, 0, 0);
        }
        _Float16* dst = sel ? Bch : Ah;
        #pragma unroll
        for (int nt = 0; nt < 5; ++nt) {
            int n = nt * 16 + c16;
            if (n < C_) {
                #pragma unroll
                for (int r = 0; r < 4; ++r)
                    dst[(m0 + 4 * g + r) * PADC + n] = (_Float16)acc[nt][r];
            }
        }
    }
}

// ---------------- Kernel 2: edge MLP, lane = edge orientation -----------
__global__ __launch_bounds__(256, 2) void edge_kernel(
    const float* __restrict__ x, const _Float16* __restrict__ Ah,
    const _Float16* __restrict__ Bch, const float* __restrict__ We1,
    const half8v* __restrict__ frags,
    const float* __restrict__ Wm, const float* __restrict__ bm,
    const float* __restrict__ Wx,
    float* __restrict__ wm_out, float* __restrict__ xacc_out)
{
    __shared__ __align__(16) _Float16 A_s[IT][PADC];
    __shared__ __align__(16) _Float16 Bc_s[P_][BCS];
    __shared__ __align__(16) float xj_s[P_][4];
    __shared__ __align__(16) _Float16 w1_s[PADC], w2_s[PADC];

    const int b  = blockIdx.x >> 4;
    const int it = blockIdx.x & 15;
    const int t  = threadIdx.x;
    const int wv = t >> 6;
    const int l  = t & 63;
    const int c16 = l & 15;
    const int g   = l >> 4;

    // ---- stage to LDS ----
    {
        const unsigned int* Asrc = (const unsigned int*)(Ah + (b * P_ + it * IT) * PADC);
        for (int idx = t; idx < IT * PADC / 2; idx += 256)
            ((unsigned int*)A_s)[idx] = Asrc[idx];
        for (int cidx = t; cidx < P_ * 10; cidx += 256) {
            int r = cidx / 10, c = cidx - r * 10;
            *(u32x4*)&Bc_s[r][c * 8] = ((const u32x4*)(Bch + (b * P_ + r) * PADC))[c];
        }
        for (int idx = t; idx < P_ * 4; idx += 256)
            ((float*)xj_s)[idx] = x[b * P_ * 4 + idx];
        if (t < 160) {
            int hs = t >= 80;
            int c = t - hs * 80;
            float wv_ = (c < C_) ? We1[(144 + hs) * C_ + c] : 0.f;
            (hs ? w2_s : w1_s)[c] = (_Float16)wv_;
        }
    }
    __syncthreads();

    // ---- We2(+be2) fragments (A-operand), coalesced precomputed loads ----
    half8v Wf[3][5];
    #pragma unroll
    for (int kt = 0; kt < 3; ++kt)
        #pragma unroll
        for (int nt = 0; nt < 5; ++nt)
            Wf[kt][nt] = frags[FRAG_WE2 + (kt * 5 + nt) * 64 + l];

    // per-lane channel table: ch = nt*16 + 4g + r
    f32x2 WmWx[5][4];
    #pragma unroll
    for (int nt = 0; nt < 5; ++nt)
        #pragma unroll
        for (int r = 0; r < 4; ++r) {
            int ch = nt * 16 + 4 * g + r;
            bool ok = ch < C_;
            WmWx[nt][r][0] = ok ? Wm[ch] : 0.f;
            WmWx[nt][r][1] = ok ? Wx[ch] : 0.f;
        }
    const float bm0 = bm[0];
    const f32x4 zero4 = {0.f, 0.f, 0.f, 0.f};

    #pragma unroll 1
    for (int ii = 0; ii < 2; ++ii) {
        const int iloc = wv * 2 + ii;
        const int i = it * IT + iloc;
        const int node_i = b * P_ + i;
        const f32x4 xi = *(const f32x4*)&xj_s[i][0];

        f32x4 wmacc[5] = {};
        f32x4 xacc = {0.f, 0.f, 0.f, 0.f};

        #pragma unroll 1
        for (int jt = 0; jt < 8; ++jt) {
            // ---- phase A: this lane's m1^T B-fragment chunks ----
            const int j = jt * 16 + c16;
            const f32x4 xjv = *(const f32x4*)&xj_s[j][0];
            float d0 = xi[0] - xjv[0], d1 = xi[1] - xjv[1];
            float d2 = xi[2] - xjv[2], d3 = xi[3] - xjv[3];
            float nn = d0 * d0 - d1 * d1 - d2 * d2 - d3 * d3;
            float pp = xi[0] * xjv[0] - xi[1] * xjv[1] - xi[2] * xjv[2] - xi[3] * xjv[3];
            _Float16 nh = (_Float16)psi_f(nn);
            _Float16 ph = (_Float16)psi_f(pp);
            half8v n8 = {nh, nh, nh, nh, nh, nh, nh, nh};
            half8v p8 = {ph, ph, ph, ph, ph, ph, ph, ph};
            half8v zero8 = {};

            auto chunk = [&](int k) -> half8v {
                half8v av = *(const half8v*)&A_s[iloc][k];
                half8v bv = *(const half8v*)&Bc_s[j][k];
                half8v w1 = *(const half8v*)&w1_s[k];
                half8v w2 = *(const half8v*)&w2_s[k];
                half8v v = av + bv;
                v = __builtin_elementwise_fma(w1, n8, v);
                v = __builtin_elementwise_fma(w2, p8, v);
                return __builtin_elementwise_max(v, zero8);
            };
            half8v af0 = chunk(g * 8);
            half8v af1 = chunk(32 + g * 8);
            half8v af2 = {};
            if (g == 0) af2 = chunk(64);
            else if (g == 1) af2[0] = (_Float16)1.0f;   // be2 bias row k=72

            // ---- phase B: D[ch][edge] = We2^T @ m1^T, 15 MFMAs ----
            f32x4 acc[5] = {};
            #pragma unroll
            for (int nt = 0; nt < 5; ++nt)
                acc[nt] = __builtin_amdgcn_mfma_f32_16x16x32_f16(Wf[0][nt], af0, acc[nt], 0, 0, 0);
            #pragma unroll
            for (int nt = 0; nt < 5; ++nt)
                acc[nt] = __builtin_amdgcn_mfma_f32_16x16x32_f16(Wf[1][nt], af1, acc[nt], 0, 0, 0);
            #pragma unroll
            for (int nt = 0; nt < 5; ++nt)
                acc[nt] = __builtin_amdgcn_mfma_f32_16x16x32_f16(Wf[2][nt], af2, acc[nt], 0, 0, 0);

            // ---- phase C: lane owns edge j; channels packed f32x4/f32x2 ----
            f32x2 wdpd = {0.f, 0.f};
            #pragma unroll
            for (int nt = 0; nt < 5; ++nt) {
                f32x4 m2q = __builtin_elementwise_max(acc[nt], zero4);  // v_pk_max_f32 x2
                acc[nt] = m2q;
                #pragma unroll
                for (int r = 0; r < 4; ++r) {
                    f32x2 vv = {m2q[r], m2q[r]};
                    wdpd = __builtin_elementwise_fma(vv, WmWx[nt][r], wdpd);
                }
            }
            // reduce across the 4 g-groups (lanes xor 16, 32)
            {
                f32x2 s;
                s[0] = __shfl_xor(wdpd[0], 16, 64);
                s[1] = __shfl_xor(wdpd[1], 16, 64);
                wdpd += s;
                s[0] = __shfl_xor(wdpd[0], 32, 64);
                s[1] = __shfl_xor(wdpd[1], 32, 64);
                wdpd += s;
            }
            float w_ = __builtin_amdgcn_rcpf(1.f + __expf(-(wdpd[0] + bm0)));
            f32x4 w4 = {w_, w_, w_, w_};
            #pragma unroll
            for (int nt = 0; nt < 5; ++nt)
                wmacc[nt] = __builtin_elementwise_fma(w4, acc[nt], wmacc[nt]); // v_pk_fma_f32 x2
            f32x4 pd4 = {wdpd[1], wdpd[1], wdpd[1], wdpd[1]};
            xacc = __builtin_elementwise_fma(pd4, xjv, xacc);
        } // jt

        // ---- finalize i: sum across the 16 edge-lanes of each row ----
        #pragma unroll
        for (int nt = 0; nt < 5; ++nt)
            #pragma unroll
            for (int r = 0; r < 4; ++r)
                wmacc[nt][r] = red16(wmacc[nt][r]);
        #pragma unroll
        for (int q = 0; q < 4; ++q) xacc[q] = red16(xacc[q]);

        if (c16 == 0) {
            #pragma unroll
            for (int nt = 0; nt < 5; ++nt)
                #pragma unroll
                for (int r = 0; r < 4; ++r) {
                    int ch = nt * 16 + 4 * g + r;
                    if (ch < C_) wm_out[node_i * C_ + ch] = wmacc[nt][r];
                }
        }
        if (l == 0)
            *(f32x4*)&xacc_out[node_i * 4] = xacc;
    } // ii
}

// ---------------- Kernel 3: node MLP (chained MFMAs, frag loads) --------
__global__ __launch_bounds__(64) void node_kernel(
    const float* __restrict__ x, const float* __restrict__ h,
    const half8v* __restrict__ frags,
    const float* __restrict__ wm, const float* __restrict__ xacc,
    float* __restrict__ hout, float* __restrict__ xout)
{
    __shared__ _Float16 g_s[16][BCS];
    const int l = threadIdx.x, c16 = l & 15, g = l >> 4;
    const int m0 = blockIdx.x * 16;

    const float* hrow  = h  + (m0 + c16) * C_;
    const float* wmrow = wm + (m0 + c16) * C_;

    // ---- GEMM1: [h|wm|1] (K=160) @ Wh1(+bh1 row 144) ----
    half8v a[5];
    #pragma unroll
    for (int kt = 0; kt < 5; ++kt) {
        int k = kt * 32 + g * 8;
        half8v v = {};
        if (k < C_) v = cvt8(hrow + k);
        else if (k < 144) v = cvt8(wmrow + (k - C_));
        else if (k == 144) v[0] = (_Float16)1.0f;
        a[kt] = v;
    }
    f32x4 acc1[5] = {};
    #pragma unroll
    for (int kt = 0; kt < 5; ++kt)
        #pragma unroll
        for (int nt = 0; nt < 5; ++nt)
            acc1[nt] = __builtin_amdgcn_mfma_f32_16x16x32_f16(
                a[kt], frags[FRAG_WH1 + (kt * 5 + nt) * 64 + l], acc1[nt], 0, 0, 0);

    // relu -> wave-local LDS transpose (D layout -> A-fragment layout)
    #pragma unroll
    for (int nt = 0; nt < 5; ++nt) {
        int n = nt * 16 + c16;
        #pragma unroll
        for (int r = 0; r < 4; ++r)
            g_s[4 * g + r][n] = (_Float16)fmaxf(acc1[nt][r], 0.f);
    }
    half8v b0 = *(const half8v*)&g_s[c16][g * 8];
    half8v b1 = *(const half8v*)&g_s[c16][32 + g * 8];
    half8v b2 = {};
    if (g == 0) b2 = *(const half8v*)&g_s[c16][64];
    else if (g == 1) b2[0] = (_Float16)1.0f;   // bh2 bias row k=72

    // ---- GEMM2: g (K=96) @ Wh2(+bh2 row 72) ----
    f32x4 acc2[5] = {};
    #pragma unroll
    for (int kt = 0; kt < 3; ++kt) {
        half8v aa = (kt == 0) ? b0 : (kt == 1 ? b1 : b2);
        #pragma unroll
        for (int nt = 0; nt < 5; ++nt)
            acc2[nt] = __builtin_amdgcn_mfma_f32_16x16x32_f16(
                aa, frags[FRAG_WH2 + (kt * 5 + nt) * 64 + l], acc2[nt], 0, 0, 0);
    }
    #pragma unroll
    for (int nt = 0; nt < 5; ++nt) {
        int n = nt * 16 + c16;
        if (n < C_) {
            #pragma unroll
            for (int r = 0; r < 4; ++r) {
                int row = m0 + 4 * g + r;
                hout[row * C_ + n] = h[row * C_ + n] + acc2[nt][r];
            }
        }
    }
    {
        int row = m0 + (l >> 2), d = l & 3;
        xout[row * 4 + d] = x[row * 4 + d] + 0.005f * (xacc[row * 4 + d] * (1.0f / 128.f));
    }
}

extern "C" void kernel_launch(void* const* d_in, const int* in_sizes, int n_in,
                              void* d_out, int out_size, void* d_ws, size_t ws_size,
                              hipStream_t stream) {
    const float* x   = (const float*)d_in[0];
    const float* h   = (const float*)d_in[1];
    const float* We1 = (const float*)d_in[2];
    const float* be1 = (const float*)d_in[3];
    const float* We2 = (const float*)d_in[4];
    const float* be2 = (const float*)d_in[5];
    const float* Wm  = (const float*)d_in[6];
    const float* bm  = (const float*)d_in[7];
    const float* Wh1 = (const float*)d_in[8];
    const float* bh1 = (const float*)d_in[9];
    const float* Wh2 = (const float*)d_in[10];
    const float* bh2 = (const float*)d_in[11];
    const float* Wx  = (const float*)d_in[12];

    const int NNODE = B_ * P_;                       // 8192
    _Float16* Ah  = (_Float16*)d_ws;                 // [8192][80] f16
    _Float16* Bch = Ah + NNODE * PADC;               // [8192][80] f16
    float* wm   = (float*)(Bch + NNODE * PADC);      // [8192][72] f32
    float* xacc = wm + NNODE * C_;                   // [8192][4]  f32
    half8v* frags = (half8v*)(xacc + NNODE * 4);     // 85 frags x 1KB

    float* hout = (float*)d_out;                     // [8192][72]
    float* xout = hout + NNODE * C_;                 // [8192][4]

    setup_kernel<<<NFRAG, 64, 0, stream>>>(We1, be1, We2, be2, Wh1, bh1, Wh2, bh2, frags);
    pre_kernel<<<NNODE / 16, 64, 0, stream>>>(h, frags, Ah, Bch);
    edge_kernel<<<B_ * 16, 256, 0, stream>>>(x, Ah, Bch, We1, frags,
                                             Wm, bm, Wx, wm, xacc);
    node_kernel<<<NNODE / 16, 64, 0, stream>>>(x, h, frags, wm, xacc, hout, xout);
}